// Round 2
// baseline (1145.236 us; speedup 1.0000x reference)
//
#include <hip/hip_runtime.h>
#include <hip/hip_bf16.h>

// B=8, N=2048, D=1024, C=1024, H=512 (fp32 in/out)
//  q = LNReLU(sgm@Wq^T+bq); k = LNReLU(velo@Wk^T+bk)
//  S = q k^T; P = softmax(S); v1 = LNReLU(velo@Wv1^T); v2 = LNReLU(sgm@Wv2^T)
//  out = concat(v2, P@v1)
//
// Round-1 crash diagnosis: assumed 320 MiB of d_ws without checking ws_size
// -> probable OOB device fault. This version: ws floor 160 MiB
// (q 64 + k 64 + v1t 32) + adaptive score staging; pre-LN Y scratch lives
// in d_out (fully overwritten later). Split-bf16 (hi+lo) 3-pass MFMA keeps
// ~fp32 accuracy (unscaled logits ~163 need abs err << 1).

#define BB 8
#define NN 2048
#define DD 1024
#define CC_ 1024
#define HH 512
#define RR (BB*NN)   // 16384 rows

typedef short bf16x8 __attribute__((ext_vector_type(8)));
typedef float f32x4  __attribute__((ext_vector_type(4)));

// ---------- helpers ----------
__device__ __forceinline__ unsigned short f2bf_rne(float x) {
    unsigned u = __float_as_uint(x);
    return (unsigned short)((u + 0x7fffu + ((u >> 16) & 1u)) >> 16);
}

__device__ __forceinline__ float wave_sum(float v) {
    #pragma unroll
    for (int o = 32; o; o >>= 1) v += __shfl_down(v, o);
    return v;
}
__device__ __forceinline__ float wave_max(float v) {
    #pragma unroll
    for (int o = 32; o; o >>= 1) v = fmaxf(v, __shfl_down(v, o));
    return v;
}

// XOR-swizzled ushort index into a [row][32] bf16 tile (64B rows).
// byte = row*64 + k*2, XOR bits 4..6 with (row&7)<<4. Preserves >=8B chunks.
__device__ __forceinline__ int swz(int row, int kshort) {
    int byte = (row << 6) | (kshort << 1);
    byte ^= (row & 7) << 4;
    return byte >> 1;
}

__device__ __forceinline__ void store_hilo(unsigned short* sh, unsigned short* sl,
                                           int row, int kq, float4 v) {
    ushort4 h, l;
    h.x = f2bf_rne(v.x); l.x = f2bf_rne(v.x - __uint_as_float((unsigned)h.x << 16));
    h.y = f2bf_rne(v.y); l.y = f2bf_rne(v.y - __uint_as_float((unsigned)h.y << 16));
    h.z = f2bf_rne(v.z); l.z = f2bf_rne(v.z - __uint_as_float((unsigned)h.z << 16));
    h.w = f2bf_rne(v.w); l.w = f2bf_rne(v.w - __uint_as_float((unsigned)h.w << 16));
    int idx = swz(row, kq);
    *(ushort4*)(sh + idx) = h;
    *(ushort4*)(sl + idx) = l;
}

// ---------- split-bf16 3-pass MFMA GEMM ----------
// C[M,N] = A[M,K] @ B[N,K]^T (K contiguous in both), tile 128x128, BK=32,
// 4 waves -> 64x64 each (4x4 frags of 16x16x32 bf16).
__global__ __launch_bounds__(256, 2)
void gemm3_kernel(const float* __restrict__ A, const float* __restrict__ B,
                  float* __restrict__ C, int K, int lda, int ldb, int ldc,
                  long sAz, long sBz, long sCz)
{
    __shared__ alignas(16) unsigned short aHi[128*32];
    __shared__ alignas(16) unsigned short aLo[128*32];
    __shared__ alignas(16) unsigned short bHi[128*32];
    __shared__ alignas(16) unsigned short bLo[128*32];

    const int bz = blockIdx.z;
    A += (long)bz * sAz;  B += (long)bz * sBz;  C += (long)bz * sCz;

    const long mbase = (long)blockIdx.y << 7;
    const long nbase = (long)blockIdx.x << 7;
    const int  t    = threadIdx.x;
    const int  wave = t >> 6, lane = t & 63;
    const int  wr = (wave >> 1) << 6;
    const int  wc = (wave & 1)  << 6;
    const int  fr = lane & 15;
    const int  kg = lane >> 4;
    const int  srow = t >> 3;
    const int  skq  = (t & 7) << 2;

    f32x4 acc[4][4] = {};

    for (int k0 = 0; k0 < K; k0 += 32) {
        #pragma unroll
        for (int i = 0; i < 4; ++i) {
            int row = srow + (i << 5);
            float4 va = *(const float4*)(A + (mbase + row) * lda + k0 + skq);
            float4 vb = *(const float4*)(B + (nbase + row) * ldb + k0 + skq);
            store_hilo(aHi, aLo, row, skq, va);
            store_hilo(bHi, bLo, row, skq, vb);
        }
        __syncthreads();

        bf16x8 ah[4], al[4], bh[4], bl[4];
        #pragma unroll
        for (int i = 0; i < 4; ++i) {
            ah[i] = *(const bf16x8*)(aHi + swz(wr + (i << 4) + fr, kg << 3));
            al[i] = *(const bf16x8*)(aLo + swz(wr + (i << 4) + fr, kg << 3));
            bh[i] = *(const bf16x8*)(bHi + swz(wc + (i << 4) + fr, kg << 3));
            bl[i] = *(const bf16x8*)(bLo + swz(wc + (i << 4) + fr, kg << 3));
        }
        #pragma unroll
        for (int i = 0; i < 4; ++i) {
            #pragma unroll
            for (int j = 0; j < 4; ++j) {
                acc[i][j] = __builtin_amdgcn_mfma_f32_16x16x32_bf16(ah[i], bh[j], acc[i][j], 0, 0, 0);
                acc[i][j] = __builtin_amdgcn_mfma_f32_16x16x32_bf16(ah[i], bl[j], acc[i][j], 0, 0, 0);
                acc[i][j] = __builtin_amdgcn_mfma_f32_16x16x32_bf16(al[i], bh[j], acc[i][j], 0, 0, 0);
            }
        }
        __syncthreads();
    }

    // C/D layout (m89): col = lane&15, row = (lane>>4)*4 + reg
    #pragma unroll
    for (int i = 0; i < 4; ++i) {
        #pragma unroll
        for (int q = 0; q < 4; ++q) {
            long grow = mbase + wr + (i << 4) + (kg << 2) + q;
            float* crow = C + grow * ldc + nbase + wc + fr;
            #pragma unroll
            for (int j = 0; j < 4; ++j) crow[j << 4] = acc[i][j][q];
        }
    }
}

// ---------- bias + LayerNorm + ReLU over rows (supports strided/in-place) ----------
template<int NC>
__global__ void ln_relu_kernel(const float* __restrict__ Y, int ldy,
                               const float* __restrict__ bias,
                               const float* __restrict__ g, const float* __restrict__ beta,
                               float* __restrict__ out, int ldo)
{
    constexpr int PER = NC / 256;
    long row = blockIdx.x;
    const float* yr = Y + row * (long)ldy;
    float* orow = out + row * (long)ldo;
    int t = threadIdx.x;
    float v[PER]; float s = 0.f, s2 = 0.f;
    #pragma unroll
    for (int i = 0; i < PER; ++i) {
        int c = t + (i << 8);
        float x = yr[c] + bias[c];
        v[i] = x; s += x; s2 += x * x;
    }
    s = wave_sum(s); s2 = wave_sum(s2);
    __shared__ float ra[4], rb[4];
    int w = t >> 6, l = t & 63;
    if (!l) { ra[w] = s; rb[w] = s2; }
    __syncthreads();
    s  = ra[0] + ra[1] + ra[2] + ra[3];
    s2 = rb[0] + rb[1] + rb[2] + rb[3];
    float mu  = s * (1.0f / NC);
    float var = s2 * (1.0f / NC) - mu * mu;
    float inv = rsqrtf(var + 1e-5f);
    #pragma unroll
    for (int i = 0; i < PER; ++i) {
        int c = t + (i << 8);
        float x = (v[i] - mu) * inv * g[c] + beta[c];
        orow[c] = fmaxf(x, 0.0f);
    }
}

// ---------- softmax over rows of 2048 (in place) ----------
__global__ void softmax2048_kernel(float* __restrict__ S)
{
    long row = blockIdx.x;
    float* r = S + row * 2048;
    int t = threadIdx.x;
    float v[8];
    float m = -1e30f;
    #pragma unroll
    for (int i = 0; i < 8; ++i) { v[i] = r[t + (i << 8)]; m = fmaxf(m, v[i]); }
    m = wave_max(m);
    __shared__ float ra[4], rb[4];
    int w = t >> 6, l = t & 63;
    if (!l) ra[w] = m;
    __syncthreads();
    m = fmaxf(fmaxf(ra[0], ra[1]), fmaxf(ra[2], ra[3]));
    float s = 0.f;
    #pragma unroll
    for (int i = 0; i < 8; ++i) { v[i] = __expf(v[i] - m); s += v[i]; }
    s = wave_sum(s);
    if (!l) rb[w] = s;
    __syncthreads();
    s = rb[0] + rb[1] + rb[2] + rb[3];
    float inv = 1.0f / s;
    #pragma unroll
    for (int i = 0; i < 8; ++i) r[t + (i << 8)] = v[i] * inv;
}

// ---------- per-batch transpose [2048,512] -> [512,2048] ----------
__global__ void transpose_kernel(const float* __restrict__ in, float* __restrict__ out)
{
    __shared__ float tile[32][33];
    long bz = blockIdx.z;
    const float* I = in  + bz * (long)NN * HH;
    float*       O = out + bz * (long)NN * HH;
    int c0 = blockIdx.x << 5, r0 = blockIdx.y << 5;
    int tx = threadIdx.x & 31, ty = threadIdx.x >> 5;   // 32 x 8
    #pragma unroll
    for (int i = 0; i < 32; i += 8)
        tile[ty + i][tx] = I[(long)(r0 + ty + i) * HH + c0 + tx];
    __syncthreads();
    #pragma unroll
    for (int i = 0; i < 32; i += 8)
        O[(long)(c0 + ty + i) * NN + r0 + tx] = tile[tx][ty + i];
}

// ---------- launch ----------
extern "C" void kernel_launch(void* const* d_in, const int* in_sizes, int n_in,
                              void* d_out, int out_size, void* d_ws, size_t ws_size,
                              hipStream_t stream)
{
    const float* sgm   = (const float*)d_in[0];
    const float* velo  = (const float*)d_in[1];
    const float* Wq    = (const float*)d_in[2];
    const float* bq    = (const float*)d_in[3];
    const float* gq    = (const float*)d_in[4];
    const float* betaq = (const float*)d_in[5];
    const float* Wk    = (const float*)d_in[6];
    const float* bk    = (const float*)d_in[7];
    const float* gk    = (const float*)d_in[8];
    const float* betak = (const float*)d_in[9];
    const float* Wv1   = (const float*)d_in[10];
    const float* bv1   = (const float*)d_in[11];
    const float* gv1   = (const float*)d_in[12];
    const float* betav1= (const float*)d_in[13];
    const float* Wv2   = (const float*)d_in[14];
    const float* bv2   = (const float*)d_in[15];
    const float* gv2   = (const float*)d_in[16];
    const float* betav2= (const float*)d_in[17];
    float* out = (float*)d_out;
    float* ws  = (float*)d_ws;

    // ws layout (floats): q 16.7M | k 16.7M | v1t 8.4M | scores bpr*4.2M
    const long Q_OFF  = 0L;
    const long K_OFF  = 16777216L;       //  64 MiB
    const long T_OFF  = 33554432L;       // 128 MiB
    const long S_OFF  = 41943040L;       // 160 MiB
    const long SCORE1 = (long)NN * NN;   // 4,194,304 floats per batch

    long ws_f = (long)(ws_size / 4);
    if (ws_f < S_OFF + SCORE1) return;   // infeasible -> clean validation fail
    int bpr = (int)((ws_f - S_OFF) / SCORE1);
    if (bpr > 8) bpr = 8;

    float* q_   = ws + Q_OFF;
    float* k_   = ws + K_OFF;
    float* v1t_ = ws + T_OFF;
    float* sc_  = ws + S_OFF;

    dim3 blk(256);

    // --- q branch: Y packed in out ---
    gemm3_kernel<<<dim3(8, 128, 1), blk, 0, stream>>>(sgm, Wq, out, DD, DD, DD, CC_, 0, 0, 0);
    ln_relu_kernel<1024><<<RR, blk, 0, stream>>>(out, CC_, bq, gq, betaq, q_, CC_);
    // --- k branch: Y packed in out ---
    gemm3_kernel<<<dim3(8, 128, 1), blk, 0, stream>>>(velo, Wk, out, DD, DD, DD, CC_, 0, 0, 0);
    ln_relu_kernel<1024><<<RR, blk, 0, stream>>>(out, CC_, bk, gk, betak, k_, CC_);
    // --- v1 branch: Y packed in out[0:8M], v1 packed in out[8M:16M] ---
    gemm3_kernel<<<dim3(4, 128, 1), blk, 0, stream>>>(velo, Wv1, out, DD, DD, DD, HH, 0, 0, 0);
    ln_relu_kernel<512><<<RR, blk, 0, stream>>>(out, HH, bv1, gv1, betav1, out + 8388608L, HH);
    transpose_kernel<<<dim3(16, 64, BB), blk, 0, stream>>>(out + 8388608L, v1t_);
    // --- v2 branch: Y strided in out[:, :512], in-place LN ---
    gemm3_kernel<<<dim3(4, 128, 1), blk, 0, stream>>>(sgm, Wv2, out, DD, DD, DD, CC_, 0, 0, 0);
    ln_relu_kernel<512><<<RR, blk, 0, stream>>>(out, CC_, bv2, gv2, betav2, out, CC_);

    // --- attention, bpr batches at a time ---
    for (int b0 = 0; b0 < BB; b0 += bpr) {
        int cnt = BB - b0 < bpr ? BB - b0 : bpr;
        gemm3_kernel<<<dim3(16, 16, cnt), blk, 0, stream>>>(
            q_ + (long)b0 * NN * CC_, k_ + (long)b0 * NN * CC_, sc_,
            CC_, CC_, CC_, NN,
            (long)NN * CC_, (long)NN * CC_, (long)NN * NN);
        softmax2048_kernel<<<cnt * NN, blk, 0, stream>>>(sc_);
        gemm3_kernel<<<dim3(4, 16, cnt), blk, 0, stream>>>(
            sc_, v1t_ + (long)b0 * HH * NN, out + (long)b0 * NN * CC_ + HH,
            NN, NN, NN, CC_,
            (long)NN * NN, (long)HH * NN, (long)NN * CC_);
    }
}

// Round 3
// 1081.513 us; speedup vs baseline: 1.0589x; 1.0589x over previous
//
#include <hip/hip_runtime.h>
#include <hip/hip_bf16.h>

// B=8, N=2048, D=1024, C=1024, H=512 (fp32 in/out)
//  q = LNReLU(sgm@Wq^T+bq); k = LNReLU(velo@Wk^T+bk)
//  S = q k^T; P = softmax(S); v1 = LNReLU(velo@Wv1^T); v2 = LNReLU(sgm@Wv2^T)
//  out = concat(v2, P@v1)
//
// Round 3: same split-bf16 3-pass math as round 2 (bit-identical => absmax
// should remain 0.015625), but operands pre-split to bf16 hi/lo and staged
// via global_load_lds (width 16) with pre-swizzled global addresses.
// ws-adaptive: full plan (pre-split inputs+weights) needs 236 MiB; fallback
// (in-kernel cvt for linears) needs 176 MiB (known-safe from round 2).

#define BB 8
#define NN 2048
#define DD 1024
#define CC_ 1024
#define HH 512
#define RR (BB*NN)   // 16384 rows

typedef unsigned short ush;
typedef short bf16x8 __attribute__((ext_vector_type(8)));
typedef float f32x4  __attribute__((ext_vector_type(4)));

#define MiB (1024L*1024L)

// ---------- helpers ----------
__device__ __forceinline__ ush f2bf_rne(float x) {
    unsigned u = __float_as_uint(x);
    return (ush)((u + 0x7fffu + ((u >> 16) & 1u)) >> 16);
}

__device__ __forceinline__ float wave_sum(float v) {
    #pragma unroll
    for (int o = 32; o; o >>= 1) v += __shfl_down(v, o);
    return v;
}
__device__ __forceinline__ float wave_max(float v) {
    #pragma unroll
    for (int o = 32; o; o >>= 1) v = fmaxf(v, __shfl_down(v, o));
    return v;
}

// LDS tile: [128 rows][32 bf16] = 64 B/row, 8 KB. Swizzle XORs byte bits 4..5
// with (row>>1)&3: involution per row (row bits >=6 untouched). A 16-lane
// b128 frag read then covers 8 distinct 16B bank slots (2-way = free, m136).
__device__ __forceinline__ int swzb(int row, int kbyte) {
    return ((row << 6) | kbyte) ^ (((row >> 1) & 3) << 4);
}

// fp32 -> (hi,lo) bf16 split, store 4 elems (8 B) into swizzled LDS tiles.
// kq = k offset in elements (multiple of 4).
__device__ __forceinline__ void store_hilo(ush* sh, ush* sl, int row, int kq, float4 v) {
    ushort4 h, l;
    h.x = f2bf_rne(v.x); l.x = f2bf_rne(v.x - __uint_as_float((unsigned)h.x << 16));
    h.y = f2bf_rne(v.y); l.y = f2bf_rne(v.y - __uint_as_float((unsigned)h.y << 16));
    h.z = f2bf_rne(v.z); l.z = f2bf_rne(v.z - __uint_as_float((unsigned)h.z << 16));
    h.w = f2bf_rne(v.w); l.w = f2bf_rne(v.w - __uint_as_float((unsigned)h.w << 16));
    int idx = swzb(row, kq << 1) >> 1;   // ushort index, 8B-aligned
    *(ushort4*)(sh + idx) = h;
    *(ushort4*)(sl + idx) = l;
}

// async global->LDS, 16 B per lane. LDS dest must be wave-uniform base
// (HW writes base + lane*16); global src is per-lane (pre-swizzled).
__device__ __forceinline__ void glds16(const void* g, void* l) {
    __builtin_amdgcn_global_load_lds(
        (const __attribute__((address_space(1))) unsigned*)g,
        (__attribute__((address_space(3))) unsigned*)l, 16, 0, 0);
}

// ---------- split-bf16 3-pass MFMA GEMM ----------
// C[M,N] = A[M,K] @ B[N,K]^T. Tile 128x128, BK=32, 4 waves -> 64x64 each.
// Passes per K-step: ah*bh, ah*bl, al*bh (same order as round 2).
// AG/BG: operand pre-split in global (hi/lo bf16 arrays, staged by glds16);
// otherwise fp32 source converted+split in-kernel (round-2 path).
// lda/ldb/strides are in elements of the respective array type.
template<bool AG, bool BG>
__global__ __launch_bounds__(256, 3)
void gemm3_kernel(const void* A0_, const void* A1_,
                  const void* B0_, const void* B1_,
                  float* __restrict__ C, int K, int lda, int ldb, int ldc,
                  long sAz, long sBz, long sCz)
{
    __shared__ alignas(16) ush aHi[128*32];
    __shared__ alignas(16) ush aLo[128*32];
    __shared__ alignas(16) ush bHi[128*32];
    __shared__ alignas(16) ush bLo[128*32];

    const long bz = blockIdx.z;
    const long mbase = (long)blockIdx.y << 7;
    const long nbase = (long)blockIdx.x << 7;
    const int  t    = threadIdx.x;
    const int  wave = t >> 6, lane = t & 63;
    const int  wr = (wave >> 1) << 6;
    const int  wc = (wave & 1)  << 6;
    const int  fr = lane & 15;
    const int  kg = lane >> 4;
    const int  srow = t >> 3;            // cvt path: row within 32-chunk
    const int  skq  = (t & 7) << 2;      // cvt path: k offset (elements)

    f32x4 acc[4][4] = {};

    for (int k0 = 0; k0 < K; k0 += 32) {
        // ---- stage A ----
        if constexpr (AG) {
            const ush* Ah = (const ush*)A0_ + bz * sAz;
            const ush* Al = (const ush*)A1_ + bz * sAz;
            #pragma unroll
            for (int i = 0; i < 2; ++i) {
                int rl = (wave << 5) + (i << 4) + (lane >> 2);
                int cs = ((lane & 3) ^ ((rl >> 1) & 3)) << 3;
                long go = (mbase + rl) * (long)lda + k0 + cs;
                glds16(Ah + go, &aHi[(wave << 10) + (i << 9)]);
                glds16(Al + go, &aLo[(wave << 10) + (i << 9)]);
            }
        } else {
            const float* Af = (const float*)A0_ + bz * sAz;
            #pragma unroll
            for (int i = 0; i < 4; ++i) {
                int row = srow + (i << 5);
                float4 va = *(const float4*)(Af + (mbase + row) * (long)lda + k0 + skq);
                store_hilo(aHi, aLo, row, skq, va);
            }
        }
        // ---- stage B ----
        if constexpr (BG) {
            const ush* Bh = (const ush*)B0_ + bz * sBz;
            const ush* Bl = (const ush*)B1_ + bz * sBz;
            #pragma unroll
            for (int i = 0; i < 2; ++i) {
                int rl = (wave << 5) + (i << 4) + (lane >> 2);
                int cs = ((lane & 3) ^ ((rl >> 1) & 3)) << 3;
                long go = (nbase + rl) * (long)ldb + k0 + cs;
                glds16(Bh + go, &bHi[(wave << 10) + (i << 9)]);
                glds16(Bl + go, &bLo[(wave << 10) + (i << 9)]);
            }
        } else {
            const float* Bf = (const float*)B0_ + bz * sBz;
            #pragma unroll
            for (int i = 0; i < 4; ++i) {
                int row = srow + (i << 5);
                float4 vb = *(const float4*)(Bf + (nbase + row) * (long)ldb + k0 + skq);
                store_hilo(bHi, bLo, row, skq, vb);
            }
        }
        __syncthreads();   // drains vmcnt (glds) + lgkmcnt (ds_write)

        bf16x8 ah[4], al[4], bh[4], bl[4];
        #pragma unroll
        for (int i = 0; i < 4; ++i) {
            int ra = wr + (i << 4) + fr, rb = wc + (i << 4) + fr;
            ah[i] = *(const bf16x8*)(aHi + (swzb(ra, kg << 4) >> 1));
            al[i] = *(const bf16x8*)(aLo + (swzb(ra, kg << 4) >> 1));
            bh[i] = *(const bf16x8*)(bHi + (swzb(rb, kg << 4) >> 1));
            bl[i] = *(const bf16x8*)(bLo + (swzb(rb, kg << 4) >> 1));
        }
        #pragma unroll
        for (int i = 0; i < 4; ++i) {
            #pragma unroll
            for (int j = 0; j < 4; ++j) {
                acc[i][j] = __builtin_amdgcn_mfma_f32_16x16x32_bf16(ah[i], bh[j], acc[i][j], 0, 0, 0);
                acc[i][j] = __builtin_amdgcn_mfma_f32_16x16x32_bf16(ah[i], bl[j], acc[i][j], 0, 0, 0);
                acc[i][j] = __builtin_amdgcn_mfma_f32_16x16x32_bf16(al[i], bh[j], acc[i][j], 0, 0, 0);
            }
        }
        __syncthreads();
    }

    float* Cb = C + bz * sCz;
    // C/D layout (m89): col = lane&15, row = (lane>>4)*4 + reg
    #pragma unroll
    for (int i = 0; i < 4; ++i) {
        #pragma unroll
        for (int q = 0; q < 4; ++q) {
            long grow = mbase + wr + (i << 4) + (kg << 2) + q;
            float* crow = Cb + grow * (long)ldc + nbase + wc + fr;
            #pragma unroll
            for (int j = 0; j < 4; ++j) crow[j << 4] = acc[i][j][q];
        }
    }
}

// ---------- bias + LayerNorm + ReLU; optional hi/lo bf16 output ----------
template<int NC, bool HILO>
__global__ void ln_relu_kernel(const float* __restrict__ Y, int ldy,
                               const float* __restrict__ bias,
                               const float* __restrict__ g, const float* __restrict__ beta,
                               float* __restrict__ outf, ush* __restrict__ oh,
                               ush* __restrict__ ol, int ldo)
{
    constexpr int PER = NC / 256;
    long row = blockIdx.x;
    const float* yr = Y + row * (long)ldy;
    int t = threadIdx.x;
    float v[PER]; float s = 0.f, s2 = 0.f;
    #pragma unroll
    for (int i = 0; i < PER; ++i) {
        int c = t + (i << 8);
        float x = yr[c] + bias[c];
        v[i] = x; s += x; s2 += x * x;
    }
    s = wave_sum(s); s2 = wave_sum(s2);
    __shared__ float ra[4], rb[4];
    int w = t >> 6, l = t & 63;
    if (!l) { ra[w] = s; rb[w] = s2; }
    __syncthreads();
    s  = ra[0] + ra[1] + ra[2] + ra[3];
    s2 = rb[0] + rb[1] + rb[2] + rb[3];
    float mu  = s * (1.0f / NC);
    float var = s2 * (1.0f / NC) - mu * mu;
    float inv = rsqrtf(var + 1e-5f);
    #pragma unroll
    for (int i = 0; i < PER; ++i) {
        int c = t + (i << 8);
        float x = (v[i] - mu) * inv * g[c] + beta[c];
        x = fmaxf(x, 0.0f);
        if constexpr (HILO) {
            ush h = f2bf_rne(x);
            ush lo = f2bf_rne(x - __uint_as_float((unsigned)h << 16));
            oh[row * (long)ldo + c] = h;
            ol[row * (long)ldo + c] = lo;
        } else {
            outf[row * (long)ldo + c] = x;
        }
    }
}

// ---------- fp32 -> hi/lo bf16 split (flat) ----------
__global__ void split_kernel(const float* __restrict__ in, ush* __restrict__ h,
                             ush* __restrict__ l, long n)
{
    long i = ((long)blockIdx.x * 256 + threadIdx.x) * 4;
    if (i >= n) return;
    float4 v = *(const float4*)(in + i);
    ushort4 hh, ll;
    hh.x = f2bf_rne(v.x); ll.x = f2bf_rne(v.x - __uint_as_float((unsigned)hh.x << 16));
    hh.y = f2bf_rne(v.y); ll.y = f2bf_rne(v.y - __uint_as_float((unsigned)hh.y << 16));
    hh.z = f2bf_rne(v.z); ll.z = f2bf_rne(v.z - __uint_as_float((unsigned)hh.z << 16));
    hh.w = f2bf_rne(v.w); ll.w = f2bf_rne(v.w - __uint_as_float((unsigned)hh.w << 16));
    *(ushort4*)(h + i) = hh;
    *(ushort4*)(l + i) = ll;
}

// ---------- softmax over rows of 2048 (in place) ----------
__global__ void softmax2048_kernel(float* __restrict__ S)
{
    long row = blockIdx.x;
    float* r = S + row * 2048;
    int t = threadIdx.x;
    float v[8];
    float m = -1e30f;
    #pragma unroll
    for (int i = 0; i < 8; ++i) { v[i] = r[t + (i << 8)]; m = fmaxf(m, v[i]); }
    m = wave_max(m);
    __shared__ float ra[4], rb[4];
    int w = t >> 6, l = t & 63;
    if (!l) ra[w] = m;
    __syncthreads();
    m = fmaxf(fmaxf(ra[0], ra[1]), fmaxf(ra[2], ra[3]));
    float s = 0.f;
    #pragma unroll
    for (int i = 0; i < 8; ++i) { v[i] = __expf(v[i] - m); s += v[i]; }
    s = wave_sum(s);
    if (!l) rb[w] = s;
    __syncthreads();
    s = rb[0] + rb[1] + rb[2] + rb[3];
    float inv = 1.0f / s;
    #pragma unroll
    for (int i = 0; i < 8; ++i) r[t + (i << 8)] = v[i] * inv;
}

// ---------- per-batch transpose [2048,512] -> [512,2048], hi/lo split ----------
__global__ void transpose_split_kernel(const float* __restrict__ in,
                                       ush* __restrict__ oh, ush* __restrict__ ol)
{
    __shared__ float tile[32][33];
    long bz = blockIdx.z;
    const float* I = in + bz * (long)NN * HH;
    ush* OH = oh + bz * (long)HH * NN;
    ush* OL = ol + bz * (long)HH * NN;
    int c0 = blockIdx.x << 5, r0 = blockIdx.y << 5;
    int tx = threadIdx.x & 31, ty = threadIdx.x >> 5;   // 32 x 8
    #pragma unroll
    for (int i = 0; i < 32; i += 8)
        tile[ty + i][tx] = I[(long)(r0 + ty + i) * HH + c0 + tx];
    __syncthreads();
    #pragma unroll
    for (int i = 0; i < 32; i += 8) {
        float x = tile[tx][ty + i];
        ush h = f2bf_rne(x);
        ush lo = f2bf_rne(x - __uint_as_float((unsigned)h << 16));
        long o = (long)(c0 + ty + i) * NN + r0 + tx;
        OH[o] = h; OL[o] = lo;
    }
}

// ---------- launch ----------
extern "C" void kernel_launch(void* const* d_in, const int* in_sizes, int n_in,
                              void* d_out, int out_size, void* d_ws, size_t ws_size,
                              hipStream_t stream)
{
    const float* sgm   = (const float*)d_in[0];
    const float* velo  = (const float*)d_in[1];
    const float* Wq    = (const float*)d_in[2];
    const float* bq    = (const float*)d_in[3];
    const float* gq    = (const float*)d_in[4];
    const float* betaq = (const float*)d_in[5];
    const float* Wk    = (const float*)d_in[6];
    const float* bk    = (const float*)d_in[7];
    const float* gk    = (const float*)d_in[8];
    const float* betak = (const float*)d_in[9];
    const float* Wv1   = (const float*)d_in[10];
    const float* bv1   = (const float*)d_in[11];
    const float* gv1   = (const float*)d_in[12];
    const float* betav1= (const float*)d_in[13];
    const float* Wv2   = (const float*)d_in[14];
    const float* bv2   = (const float*)d_in[15];
    const float* gv2   = (const float*)d_in[16];
    const float* betav2= (const float*)d_in[17];
    float* out = (float*)d_out;
    char*  wsb = (char*)d_ws;
    long   wsB = (long)ws_size;

    dim3 blk(256);
    const bool full = wsB >= 236 * MiB;

    // common regions
    ush *qh, *ql, *kh, *kl, *v1th, *v1tl;
    float* sc;
    int bpr;

    if (full) {
        // [xh 32][xl 32][W 12][qh 32][ql 32][kh 32][kl 32][v1th 16][v1tl 16]
        // S reuses the x region during attention (x dead by then).
        qh   = (ush*)(wsb +  76 * MiB);
        ql   = (ush*)(wsb + 108 * MiB);
        kh   = (ush*)(wsb + 140 * MiB);
        kl   = (ush*)(wsb + 172 * MiB);
        v1th = (ush*)(wsb + 204 * MiB);
        v1tl = (ush*)(wsb + 220 * MiB);
        sc   = (float*)wsb;
        bpr  = 4;                       // 4 * 16 MiB fits the 64 MiB x region
    } else {
        if (wsB < 176 * MiB) return;    // infeasible -> clean validation fail
        // round-2 footprint: [qh 32][ql 32][kh 32][kl 32][v1th 16][v1tl 16][S ...]
        qh   = (ush*)(wsb);
        ql   = (ush*)(wsb +  32 * MiB);
        kh   = (ush*)(wsb +  64 * MiB);
        kl   = (ush*)(wsb +  96 * MiB);
        v1th = (ush*)(wsb + 128 * MiB);
        v1tl = (ush*)(wsb + 144 * MiB);
        sc   = (float*)(wsb + 160 * MiB);
        bpr  = (int)((wsB - 160 * MiB) / (16 * MiB));
        if (bpr > 8) bpr = 8;
    }

    float* v1f = out + 8388608L;        // v1 fp32 staging (out bytes 32..64 MiB)

    if (full) {
        ush* xh = (ush*)wsb;
        ush* xl = (ush*)(wsb + 32 * MiB);
        ush* Wqh  = (ush*)(wsb + 64 * MiB);
        ush* Wql  = (ush*)(wsb + 66 * MiB);
        ush* Wkh  = (ush*)(wsb + 68 * MiB);
        ush* Wkl  = (ush*)(wsb + 70 * MiB);
        ush* Wv1h = (ush*)(wsb + 72 * MiB);
        ush* Wv1l = (ush*)(wsb + 73 * MiB);
        ush* Wv2h = (ush*)(wsb + 74 * MiB);
        ush* Wv2l = (ush*)(wsb + 75 * MiB);

        split_kernel<<<1024, blk, 0, stream>>>(Wq,  Wqh,  Wql,  (long)CC_*DD);
        split_kernel<<<1024, blk, 0, stream>>>(Wk,  Wkh,  Wkl,  (long)CC_*DD);
        split_kernel<<<512,  blk, 0, stream>>>(Wv1, Wv1h, Wv1l, (long)HH*DD);
        split_kernel<<<512,  blk, 0, stream>>>(Wv2, Wv2h, Wv2l, (long)HH*DD);

        // velo-derived branches
        split_kernel<<<16384, blk, 0, stream>>>(velo, xh, xl, (long)RR*DD);
        gemm3_kernel<true,true><<<dim3(8,128,1), blk, 0, stream>>>(
            xh, xl, Wkh, Wkl, out, DD, DD, DD, CC_, 0, 0, 0);
        ln_relu_kernel<1024,true><<<RR, blk, 0, stream>>>(out, CC_, bk, gk, betak, nullptr, kh, kl, CC_);
        gemm3_kernel<true,true><<<dim3(4,128,1), blk, 0, stream>>>(
            xh, xl, Wv1h, Wv1l, out, DD, DD, DD, HH, 0, 0, 0);
        ln_relu_kernel<512,false><<<RR, blk, 0, stream>>>(out, HH, bv1, gv1, betav1, v1f, nullptr, nullptr, HH);
        transpose_split_kernel<<<dim3(16,64,BB), blk, 0, stream>>>(v1f, v1th, v1tl);

        // sgm-derived branches (x region reused)
        split_kernel<<<16384, blk, 0, stream>>>(sgm, xh, xl, (long)RR*DD);
        gemm3_kernel<true,true><<<dim3(8,128,1), blk, 0, stream>>>(
            xh, xl, Wqh, Wql, out, DD, DD, DD, CC_, 0, 0, 0);
        ln_relu_kernel<1024,true><<<RR, blk, 0, stream>>>(out, CC_, bq, gq, betaq, nullptr, qh, ql, CC_);
        gemm3_kernel<true,true><<<dim3(4,128,1), blk, 0, stream>>>(
            xh, xl, Wv2h, Wv2l, out, DD, DD, DD, CC_, 0, 0, 0);
        ln_relu_kernel<512,false><<<RR, blk, 0, stream>>>(out, CC_, bv2, gv2, betav2, out, nullptr, nullptr, CC_);
    } else {
        gemm3_kernel<false,false><<<dim3(8,128,1), blk, 0, stream>>>(
            velo, nullptr, Wk, nullptr, out, DD, DD, DD, CC_, 0, 0, 0);
        ln_relu_kernel<1024,true><<<RR, blk, 0, stream>>>(out, CC_, bk, gk, betak, nullptr, kh, kl, CC_);
        gemm3_kernel<false,false><<<dim3(4,128,1), blk, 0, stream>>>(
            velo, nullptr, Wv1, nullptr, out, DD, DD, DD, HH, 0, 0, 0);
        ln_relu_kernel<512,false><<<RR, blk, 0, stream>>>(out, HH, bv1, gv1, betav1, v1f, nullptr, nullptr, HH);
        transpose_split_kernel<<<dim3(16,64,BB), blk, 0, stream>>>(v1f, v1th, v1tl);

        gemm3_kernel<false,false><<<dim3(8,128,1), blk, 0, stream>>>(
            sgm, nullptr, Wq, nullptr, out, DD, DD, DD, CC_, 0, 0, 0);
        ln_relu_kernel<1024,true><<<RR, blk, 0, stream>>>(out, CC_, bq, gq, betaq, nullptr, qh, ql, CC_);
        gemm3_kernel<false,false><<<dim3(4,128,1), blk, 0, stream>>>(
            sgm, nullptr, Wv2, nullptr, out, DD, DD, DD, CC_, 0, 0, 0);
        ln_relu_kernel<512,false><<<RR, blk, 0, stream>>>(out, CC_, bv2, gv2, betav2, out, nullptr, nullptr, CC_);
    }

    // ---- attention: S = q k^T per batch, softmax, out[:,512:] = P @ v1 ----
    for (int b0 = 0; b0 < BB; b0 += bpr) {
        int cnt = BB - b0 < bpr ? BB - b0 : bpr;
        gemm3_kernel<true,true><<<dim3(16,16,cnt), blk, 0, stream>>>(
            qh + (long)b0 * NN * CC_, ql + (long)b0 * NN * CC_,
            kh + (long)b0 * NN * CC_, kl + (long)b0 * NN * CC_,
            sc, CC_, CC_, CC_, NN,
            (long)NN * CC_, (long)NN * CC_, (long)NN * NN);
        softmax2048_kernel<<<cnt * NN, blk, 0, stream>>>(sc);
        gemm3_kernel<false,true><<<dim3(4,16,cnt), blk, 0, stream>>>(
            sc, nullptr,
            v1th + (long)b0 * HH * NN, v1tl + (long)b0 * HH * NN,
            out + (long)b0 * NN * CC_ + HH,
            NN, NN, NN, CC_,
            (long)NN * NN, (long)HH * NN, (long)NN * CC_);
    }
}